// Round 15
// baseline (300.811 us; speedup 1.0000x reference)
//
#include <hip/hip_runtime.h>
#include <cfloat>

#define NPTS   16384
#define MATOMS 8192
#define CH     16
#define ADIM   6
#define KNN    16
#define GROUPS_PER_BLOCK 8     // 32-lane groups; each group serves 2 points
#define PTSPG  2
#define BIGF   1e10f
#define SLOTS  10              // per-lane per-point capacity (lambda~2, P(>10)~8e-6)
#define CHUNK  512
#define NCHUNK (MATOMS/CHUNK)  // 16
#define VMINC  4               // vmin subset = first 2048 atoms (r10-validated)
#define NPASS  (VMINC + NCHUNK) // 20

__device__ __forceinline__ float leakyf(float x) { return x >= 0.0f ? x : 0.2f * x; }

// ---------------------------------------------------------------------------
// Kernel A: per-atom feature MLP t = L3(L2(L1(atomtypes))) + packed pos4
// ---------------------------------------------------------------------------
__global__ void __launch_bounds__(256) prep_kernel(
    const float* __restrict__ atom_xyz,
    const float* __restrict__ atomtypes,
    const int*   __restrict__ atom_batch,
    const float* __restrict__ Wt1, const float* __restrict__ bt1,
    const float* __restrict__ Wt2, const float* __restrict__ bt2,
    const float* __restrict__ Wt3, const float* __restrict__ bt3,
    float4* __restrict__ pos4,
    float*  __restrict__ tbuf,
    int*    __restrict__ abatch)
{
    __shared__ float w1[CH*ADIM], w2[CH*CH], w3[CH*CH], bb1[CH], bb2[CH], bb3[CH];
    const int tid = threadIdx.x;
    if (tid < CH*ADIM) w1[tid] = Wt1[tid];
    if (tid < CH*CH)   { w2[tid] = Wt2[tid]; w3[tid] = Wt3[tid]; }
    if (tid < CH)      { bb1[tid] = bt1[tid]; bb2[tid] = bt2[tid]; bb3[tid] = bt3[tid]; }
    __syncthreads();
    const int m = blockIdx.x * 256 + tid;
    if (m >= MATOMS) return;

    float x[ADIM];
    #pragma unroll
    for (int j = 0; j < ADIM; ++j) x[j] = atomtypes[m*ADIM + j];

    float h0[CH], h1[CH], h2[CH];
    #pragma unroll
    for (int c = 0; c < CH; ++c) {
        float a = 0.0f;
        #pragma unroll
        for (int j = 0; j < ADIM; ++j) a = fmaf(w1[c*ADIM+j], x[j], a);
        h0[c] = leakyf(a + bb1[c]);
    }
    #pragma unroll
    for (int c = 0; c < CH; ++c) {
        float a = 0.0f;
        #pragma unroll
        for (int j = 0; j < CH; ++j) a = fmaf(w2[c*CH+j], h0[j], a);
        h1[c] = leakyf(a + bb2[c]);
    }
    #pragma unroll
    for (int c = 0; c < CH; ++c) {
        float a = 0.0f;
        #pragma unroll
        for (int j = 0; j < CH; ++j) a = fmaf(w3[c*CH+j], h1[j], a);
        h2[c] = leakyf(a + bb3[c]);
    }
    #pragma unroll
    for (int c = 0; c < CH; ++c) tbuf[m*CH + c] = h2[c];

    const float ax = atom_xyz[m*3+0], ay = atom_xyz[m*3+1], az = atom_xyz[m*3+2];
    // np: sum(a*a, -1) = ((ax^2 + ay^2) + az^2), no FMA contraction
    const float a2 = __fadd_rn(__fadd_rn(__fmul_rn(ax,ax), __fmul_rn(ay,ay)), __fmul_rn(az,az));
    pos4[m] = make_float4(ax, ay, az, a2);
    abatch[m] = atom_batch[m];
}

// ---------------------------------------------------------------------------
// Per-point tail: overflow guard -> (fallback full insert-scan | phase C
// exact select) -> final lexicographic pop-min merge. Validated bodies.
// ---------------------------------------------------------------------------
__device__ __forceinline__ void knn_tail(
    int c32, float px, float py, float pz, float pn2, int pb,
    int skip, int cnt, const unsigned short* seg,
    const float4* __restrict__ pos4, const int* __restrict__ abatch,
    int* idxk)
{
    int ovf = skip | (cnt > SLOTS);
    ovf |= __shfl_xor(ovf, 1);
    ovf |= __shfl_xor(ovf, 2);
    ovf |= __shfl_xor(ovf, 4);
    ovf |= __shfl_xor(ovf, 8);
    ovf |= __shfl_xor(ovf, 16);

    float bd[KNN]; int bi[KNN];
    #pragma unroll
    for (int j = 0; j < KNN; ++j) { bd[j] = FLT_MAX; bi[j] = 0x7fffffff; }

    if (ovf) {
        // validated full insert-scan fallback (rare; group-uniform)
        for (int t = 0; t < MATOMS/32; ++t) {
            const int i = t*32 + c32;
            const float4 a = pos4[i];
            const int ab = abatch[i];
            const float dot = fmaf(pz, a.z, fmaf(py, a.y, __fmul_rn(px, a.x)));
            float d2 = __fsub_rn(__fadd_rn(pn2, a.w), 2.0f * dot);
            d2 = (ab == pb) ? d2 : BIGF;
            if (d2 < bd[KNN-1]) {
                float d = d2; int id = i;
                #pragma unroll
                for (int j = 0; j < KNN; ++j) {
                    const bool sw = d < bd[j];
                    const float od = bd[j]; const int oi = bi[j];
                    bd[j] = sw ? d  : bd[j];
                    bi[j] = sw ? id : bi[j];
                    d  = sw ? od : d;
                    id = sw ? oi : id;
                }
            }
        }
    } else {
        // Phase C: EXACT d2 recompute + EXACT batch check + lexicographic
        // (d, idx) insert (order-independent-exact).
        for (int s = 0; s < cnt; ++s) {
            const int i = (int)seg[s*32];
            const float4 a = pos4[i];
            const float dot = fmaf(pz, a.z, fmaf(py, a.y, __fmul_rn(px, a.x)));
            const float d2 = __fsub_rn(__fadd_rn(pn2, a.w), 2.0f * dot);
            if (abatch[i] == pb && d2 <= bd[KNN-1]) {
                float d = d2; int id = i;
                #pragma unroll
                for (int j = 0; j < KNN; ++j) {
                    const bool sw = (d < bd[j]) || (d == bd[j] && id < bi[j]);
                    const float od = bd[j]; const int oi = bi[j];
                    bd[j] = sw ? d  : bd[j];
                    bi[j] = sw ? id : bi[j];
                    d  = sw ? od : d;
                    id = sw ? oi : id;
                }
            }
        }
    }

    // final merge: 16x pop-min over 32 lanes, lexicographic (d, idx)
    #pragma unroll
    for (int k = 0; k < KNN; ++k) {
        float d = bd[0]; int i = bi[0];
        #pragma unroll
        for (int m = 1; m <= 16; m <<= 1) {
            const float pd = __shfl_xor(d, m);
            const int   pi = __shfl_xor(i, m);
            const bool take = (pd < d) || (pd == d && pi < i);
            d = take ? pd : d;
            i = take ? pi : i;
        }
        idxk[k] = i;
        const bool win = (bd[0] == d) && (bi[0] == i);
        if (win) {
            #pragma unroll
            for (int j = 0; j < KNN-1; ++j) { bd[j] = bd[j+1]; bi[j] = bi[j+1]; }
            bd[KNN-1] = FLT_MAX; bi[KNN-1] = 0x7fffffff;
        }
    }
}

// ---------------------------------------------------------------------------
// Kernel B: 32-lane groups, 2 POINTS per group (1024 blocks, ~29.9 KB LDS
//   -> 5 blocks/CU). r14-validated schedule; staged atoms PRE-SCALED as
//   (-2x,-2y,-2z,a2) so the screen value is a pure 3-FMA chain:
//     lhs' = fma(pz,bz, fma(py,by, fma(px,bx, a2)))
//   tau and the filter share lhs'-space (validity argument space-agnostic);
//   slack 1e-2 >> 2*|d2-(pn2+lhs')| ~ 2e-4; phase C recomputes EXACT d2.
// ---------------------------------------------------------------------------
__global__ void __launch_bounds__(256) atom_main_kernel(
    const float* __restrict__ xyz,
    const int*   __restrict__ batch,
    const float4* __restrict__ pos4,
    const float* __restrict__ tbuf,
    const int*   __restrict__ abatch,
    const float* __restrict__ Watt,
    const float* __restrict__ We1, const float* __restrict__ be1,
    const float* __restrict__ We2, const float* __restrict__ be2,
    const float* __restrict__ We3, const float* __restrict__ be3,
    float* __restrict__ out)
{
    __shared__ float lw1t[CH*CH], lw2t[CH*CH], lw3t[CH*CH];
    __shared__ float lb1[CH], lb2[CH], lb3[CH], lwatt[KNN];
    __shared__ unsigned short lbuf[GROUPS_PER_BLOCK * PTSPG * SLOTS * 32];
    __shared__ float4 lpos[2][CHUNK];
    const int tid = threadIdx.x;
    lw1t[tid] = We1[(tid & 15)*CH + (tid >> 4)];
    lw2t[tid] = We2[(tid & 15)*CH + (tid >> 4)];
    lw3t[tid] = We3[(tid & 15)*CH + (tid >> 4)];
    if (tid < CH) { lb1[tid] = be1[tid]; lb2[tid] = be2[tid]; lb3[tid] = be3[tid]; lwatt[tid] = Watt[tid]; }

    const int c32 = tid & 31;
    const int grp = tid >> 5;
    const int n0  = (blockIdx.x * GROUPS_PER_BLOCK + grp) * PTSPG;
    const int n1  = n0 + 1;

    const float px0 = xyz[n0*3+0], py0 = xyz[n0*3+1], pz0 = xyz[n0*3+2];
    const float px1 = xyz[n1*3+0], py1 = xyz[n1*3+1], pz1 = xyz[n1*3+2];
    // np: sum(x*x, -1) sequential, no FMA
    const float pn20 = __fadd_rn(__fadd_rn(__fmul_rn(px0,px0), __fmul_rn(py0,py0)), __fmul_rn(pz0,pz0));
    const float pn21 = __fadd_rn(__fadd_rn(__fmul_rn(px1,px1), __fmul_rn(py1,py1)), __fmul_rn(pz1,pz1));
    const int pb0 = batch[n0];
    const int pb1 = batch[n1];

    // prologue: stage chunk 0 into buffer 0 (pre-scaled; -2*x is exact)
    {
        const float4 q0 = pos4[tid];
        const float4 q1 = pos4[tid+256];
        lpos[0][tid]     = make_float4(-2.0f*q0.x, -2.0f*q0.y, -2.0f*q0.z, q0.w);
        lpos[0][tid+256] = make_float4(-2.0f*q1.x, -2.0f*q1.y, -2.0f*q1.z, q1.w);
    }

    float vmin0 = FLT_MAX, vmin1 = FLT_MAX;
    float tauf0 = 0.0f, tauf1 = 0.0f;
    int   skip0 = 0, skip1 = 0;
    int   cnt0 = 0, cnt1 = 0;
    unsigned short* seg0 = &lbuf[(grp*PTSPG + 0) * (SLOTS*32) + c32];
    unsigned short* seg1 = &lbuf[(grp*PTSPG + 1) * (SLOTS*32) + c32];

    for (int g = 0; g < NPASS; ++g) {
        const int cur = g & 1;
        __syncthreads();                     // buf[cur] ready; buf[cur^1] free
        // issue next-chunk loads AFTER the barrier (not drained by it)
        float4 q0, q1;
        const bool pf = (g+1 < NPASS);
        if (pf) {
            const int nc = (g+1 < VMINC) ? (g+1) : (g+1-VMINC);
            const int base = nc*CHUNK;
            q0 = pos4[base+tid]; q1 = pos4[base+tid+256];
        }
        if (g == VMINC) {
            // per-point tau: 16 d-only pop-mins over 32 lane minima (lhs'-
            // space). Validity: each pop removes >=1 lane = >=1 distinct
            // in-batch atom with lhs' <= tau.
            float tau0 = FLT_MAX, tau1 = FLT_MAX;
            {
                float v = vmin0;
                #pragma unroll
                for (int k = 0; k < KNN; ++k) {
                    float d = v;
                    d = fminf(d, __shfl_xor(d, 1));
                    d = fminf(d, __shfl_xor(d, 2));
                    d = fminf(d, __shfl_xor(d, 4));
                    d = fminf(d, __shfl_xor(d, 8));
                    d = fminf(d, __shfl_xor(d, 16));
                    tau0 = d;
                    if (v == d) v = FLT_MAX; // remove popped (ties safe)
                }
            }
            {
                float v = vmin1;
                #pragma unroll
                for (int k = 0; k < KNN; ++k) {
                    float d = v;
                    d = fminf(d, __shfl_xor(d, 1));
                    d = fminf(d, __shfl_xor(d, 2));
                    d = fminf(d, __shfl_xor(d, 4));
                    d = fminf(d, __shfl_xor(d, 8));
                    d = fminf(d, __shfl_xor(d, 16));
                    tau1 = d;
                    if (v == d) v = FLT_MAX;
                }
            }
            skip0 = !(tau0 < BIGF);          // group-uniform
            skip1 = !(tau1 < BIGF);
            tauf0 = skip0 ? -FLT_MAX : tau0 + (1e-5f*(fabsf(pn20) + fabsf(tau0)) + 1e-2f);
            tauf1 = skip1 ? -FLT_MAX : tau1 + (1e-5f*(fabsf(pn21) + fabsf(tau1)) + 1e-2f);
        }
        if (g < VMINC) {
            // dual vmin scan (subset chunks 0..3); lazy global batch check
            #pragma unroll 4
            for (int t = 0; t < CHUNK/32; ++t) {
                const int il = t*32 + c32;
                const float4 a = lpos[cur][il];
                const float lhs0 = fmaf(pz0, a.z, fmaf(py0, a.y, fmaf(px0, a.x, a.w)));
                const float lhs1 = fmaf(pz1, a.z, fmaf(py1, a.y, fmaf(px1, a.x, a.w)));
                if (lhs0 < vmin0) { if (abatch[g*CHUNK + il] == pb0) vmin0 = lhs0; }
                if (lhs1 < vmin1) { if (abatch[g*CHUNK + il] == pb1) vmin1 = lhs1; }
            }
        } else {
            // dual lean distance-only filter scan (3 FMA + cmp per point)
            const int cb = g - VMINC;
            #pragma unroll 4
            for (int t = 0; t < CHUNK/32; ++t) {
                const int il = t*32 + c32;
                const float4 a = lpos[cur][il];
                const float lhs0 = fmaf(pz0, a.z, fmaf(py0, a.y, fmaf(px0, a.x, a.w)));
                const float lhs1 = fmaf(pz1, a.z, fmaf(py1, a.y, fmaf(px1, a.x, a.w)));
                const int gi = cb*CHUNK + il;
                if (lhs0 <= tauf0) {
                    if (cnt0 < SLOTS) seg0[cnt0*32] = (unsigned short)gi;
                    ++cnt0;
                }
                if (lhs1 <= tauf1) {
                    if (cnt1 < SLOTS) seg1[cnt1*32] = (unsigned short)gi;
                    ++cnt1;
                }
            }
        }
        if (pf) {                            // write-late: loads landed by now
            lpos[cur^1][tid]     = make_float4(-2.0f*q0.x, -2.0f*q0.y, -2.0f*q0.z, q0.w);
            lpos[cur^1][tid+256] = make_float4(-2.0f*q1.x, -2.0f*q1.y, -2.0f*q1.z, q1.w);
        }
    }

    // ---- tails (validated): exact selection per point
    int idxk0[KNN], idxk1[KNN];
    knn_tail(c32, px0, py0, pz0, pn20, pb0, skip0, cnt0, seg0, pos4, abatch, idxk0);
    knn_tail(c32, px1, py1, pz1, pn21, pb1, skip1, cnt1, seg1, pos4, abatch, idxk1);

    // ---- packed epilogue: lanes 0-15 -> point0, lanes 16-31 -> point1.
    {
        const int half = (tid >> 4) & 1;
        const int c = tid & 15;
        const int myn = half ? n1 : n0;
        const float px = half ? px1 : px0;
        const float py = half ? py1 : py0;
        const float pz = half ? pz1 : pz0;
        int myidx[KNN];
        #pragma unroll
        for (int k = 0; k < KNN; ++k) myidx[k] = half ? idxk1[k] : idxk0[k];

        float ac0 = 0.0f, ac1 = 0.0f, ac2 = 0.0f;
        #pragma unroll
        for (int k = 0; k < KNN; ++k) {
            const int j = myidx[k];
            const float4 a = pos4[j];
            const float v0 = __fsub_rn(px, a.x);
            const float v1 = __fsub_rn(py, a.y);
            const float v2 = __fsub_rn(pz, a.z);
            // np: dists = sum(vecs*vecs, -1), sequential, no FMA (recomputed)
            const float dist = __fadd_rn(__fadd_rn(__fmul_rn(v0,v0), __fmul_rn(v1,v1)), __fmul_rn(v2,v2));
            const float w = 1.0f / __fadd_rn(dist, 1e-8f);   // power(x, -1.0)
            const float nv0 = __fmul_rn(v0, w);
            const float nv1 = __fmul_rn(v1, w);
            const float nv2 = __fmul_rn(v2, w);
            const float fc = tbuf[(size_t)j * CH + c];
            const float fw = __fmul_rn(fc, lwatt[k]);
            ac0 = fmaf(nv0, fw, ac0);
            ac1 = fmaf(nv1, fw, ac1);
            ac2 = fmaf(nv2, fw, ac2);
        }
        const float s = __fadd_rn(__fadd_rn(__fmul_rn(ac0,ac0), __fmul_rn(ac1,ac1)),
                                  __fmul_rn(ac2,ac2));
        const float fx = sqrtf(s);

        float a1 = 0.0f;
        #pragma unroll
        for (int j = 0; j < CH; ++j) {
            const float fj = __shfl(fx, j, 16);
            a1 = fmaf(lw1t[j*CH + c], fj, a1);
        }
        const float g1 = leakyf(a1 + lb1[c]);

        float a2 = 0.0f;
        #pragma unroll
        for (int j = 0; j < CH; ++j) {
            const float gj = __shfl(g1, j, 16);
            a2 = fmaf(lw2t[j*CH + c], gj, a2);
        }
        const float g2 = leakyf(a2 + lb2[c]);

        float a3 = 0.0f;
        #pragma unroll
        for (int j = 0; j < CH; ++j) {
            const float gj = __shfl(g2, j, 16);
            a3 = fmaf(lw3t[j*CH + c], gj, a3);
        }
        out[(size_t)myn*CH + c] = a3 + lb3[c];
    }
}

// ---------------------------------------------------------------------------
extern "C" void kernel_launch(void* const* d_in, const int* in_sizes, int n_in,
                              void* d_out, int out_size, void* d_ws, size_t ws_size,
                              hipStream_t stream)
{
    (void)in_sizes; (void)n_in; (void)out_size; (void)ws_size;
    const float* xyz        = (const float*)d_in[0];
    const float* atom_xyz   = (const float*)d_in[1];
    const float* atomtypes  = (const float*)d_in[2];
    const int*   batch      = (const int*)d_in[3];
    const int*   atom_batch = (const int*)d_in[4];
    const float* Wt1 = (const float*)d_in[5];
    const float* bt1 = (const float*)d_in[6];
    const float* Wt2 = (const float*)d_in[7];
    const float* bt2 = (const float*)d_in[8];
    const float* Wt3 = (const float*)d_in[9];
    const float* bt3 = (const float*)d_in[10];
    const float* Watt = (const float*)d_in[11];
    const float* We1 = (const float*)d_in[12];
    const float* be1 = (const float*)d_in[13];
    const float* We2 = (const float*)d_in[14];
    const float* be2 = (const float*)d_in[15];
    const float* We3 = (const float*)d_in[16];
    const float* be3 = (const float*)d_in[17];

    char* ws = (char*)d_ws;
    float4* pos4  = (float4*)ws;                          // 8192*16  = 131072 B
    float*  tbuf  = (float*)(ws + 131072);                // 8192*64  = 524288 B
    int*    abat  = (int*)(ws + 131072 + 524288);         // 8192*4   =  32768 B
    float*  out   = (float*)d_out;

    hipLaunchKernelGGL(prep_kernel, dim3(MATOMS/256), dim3(256), 0, stream,
                       atom_xyz, atomtypes, atom_batch,
                       Wt1, bt1, Wt2, bt2, Wt3, bt3,
                       pos4, tbuf, abat);
    hipLaunchKernelGGL(atom_main_kernel, dim3(NPTS/(GROUPS_PER_BLOCK*PTSPG)), dim3(256), 0, stream,
                       xyz, batch, pos4, tbuf, abat,
                       Watt, We1, be1, We2, be2, We3, be3,
                       out);
}

// Round 16
// 119.634 us; speedup vs baseline: 2.5144x; 2.5144x over previous
//
#include <hip/hip_runtime.h>
#include <cfloat>

#define NPTS   16384
#define MATOMS 8192
#define CH     16
#define ADIM   6
#define KNN    16
#define GROUPS_PER_BLOCK 8     // 32-lane groups; each group serves 2 points
#define PTSPG  2
#define BIGF   1e10f
#define SLOTS  16              // per-lane per-point capacity (lambda~2.7, P(>16)~1e-8)
#define CHUNK  512
#define NCHUNK (MATOMS/CHUNK)  // 16
#define VMINC  4               // vmin subset = first 2048 atoms (r10-validated)
#define NPASS  (VMINC + NCHUNK) // 20

__device__ __forceinline__ float leakyf(float x) { return x >= 0.0f ? x : 0.2f * x; }

// ---------------------------------------------------------------------------
// Kernel A: per-atom feature MLP t = L3(L2(L1(atomtypes))) + packed pos4
// ---------------------------------------------------------------------------
__global__ void __launch_bounds__(256) prep_kernel(
    const float* __restrict__ atom_xyz,
    const float* __restrict__ atomtypes,
    const int*   __restrict__ atom_batch,
    const float* __restrict__ Wt1, const float* __restrict__ bt1,
    const float* __restrict__ Wt2, const float* __restrict__ bt2,
    const float* __restrict__ Wt3, const float* __restrict__ bt3,
    float4* __restrict__ pos4,
    float*  __restrict__ tbuf,
    int*    __restrict__ abatch)
{
    __shared__ float w1[CH*ADIM], w2[CH*CH], w3[CH*CH], bb1[CH], bb2[CH], bb3[CH];
    const int tid = threadIdx.x;
    if (tid < CH*ADIM) w1[tid] = Wt1[tid];
    if (tid < CH*CH)   { w2[tid] = Wt2[tid]; w3[tid] = Wt3[tid]; }
    if (tid < CH)      { bb1[tid] = bt1[tid]; bb2[tid] = bt2[tid]; bb3[tid] = bt3[tid]; }
    __syncthreads();
    const int m = blockIdx.x * 256 + tid;
    if (m >= MATOMS) return;

    float x[ADIM];
    #pragma unroll
    for (int j = 0; j < ADIM; ++j) x[j] = atomtypes[m*ADIM + j];

    float h0[CH], h1[CH], h2[CH];
    #pragma unroll
    for (int c = 0; c < CH; ++c) {
        float a = 0.0f;
        #pragma unroll
        for (int j = 0; j < ADIM; ++j) a = fmaf(w1[c*ADIM+j], x[j], a);
        h0[c] = leakyf(a + bb1[c]);
    }
    #pragma unroll
    for (int c = 0; c < CH; ++c) {
        float a = 0.0f;
        #pragma unroll
        for (int j = 0; j < CH; ++j) a = fmaf(w2[c*CH+j], h0[j], a);
        h1[c] = leakyf(a + bb2[c]);
    }
    #pragma unroll
    for (int c = 0; c < CH; ++c) {
        float a = 0.0f;
        #pragma unroll
        for (int j = 0; j < CH; ++j) a = fmaf(w3[c*CH+j], h1[j], a);
        h2[c] = leakyf(a + bb3[c]);
    }
    #pragma unroll
    for (int c = 0; c < CH; ++c) tbuf[m*CH + c] = h2[c];

    const float ax = atom_xyz[m*3+0], ay = atom_xyz[m*3+1], az = atom_xyz[m*3+2];
    // np: sum(a*a, -1) = ((ax^2 + ay^2) + az^2), no FMA contraction
    const float a2 = __fadd_rn(__fadd_rn(__fmul_rn(ax,ax), __fmul_rn(ay,ay)), __fmul_rn(az,az));
    pos4[m] = make_float4(ax, ay, az, a2);
    abatch[m] = atom_batch[m];
}

// ---------------------------------------------------------------------------
// Per-point tail: overflow guard -> (fallback full insert-scan | phase C
// exact select) -> final lexicographic pop-min merge. Validated bodies.
// ---------------------------------------------------------------------------
__device__ __forceinline__ void knn_tail(
    int c32, float px, float py, float pz, float pn2, int pb,
    int skip, int cnt, const unsigned short* seg,
    const float4* __restrict__ pos4, const int* __restrict__ abatch,
    int* idxk)
{
    int ovf = skip | (cnt > SLOTS);
    ovf |= __shfl_xor(ovf, 1);
    ovf |= __shfl_xor(ovf, 2);
    ovf |= __shfl_xor(ovf, 4);
    ovf |= __shfl_xor(ovf, 8);
    ovf |= __shfl_xor(ovf, 16);

    float bd[KNN]; int bi[KNN];
    #pragma unroll
    for (int j = 0; j < KNN; ++j) { bd[j] = FLT_MAX; bi[j] = 0x7fffffff; }

    if (ovf) {
        // validated full insert-scan fallback (rare; group-uniform)
        for (int t = 0; t < MATOMS/32; ++t) {
            const int i = t*32 + c32;
            const float4 a = pos4[i];
            const int ab = abatch[i];
            const float dot = fmaf(pz, a.z, fmaf(py, a.y, __fmul_rn(px, a.x)));
            float d2 = __fsub_rn(__fadd_rn(pn2, a.w), 2.0f * dot);
            d2 = (ab == pb) ? d2 : BIGF;
            if (d2 < bd[KNN-1]) {
                float d = d2; int id = i;
                #pragma unroll
                for (int j = 0; j < KNN; ++j) {
                    const bool sw = d < bd[j];
                    const float od = bd[j]; const int oi = bi[j];
                    bd[j] = sw ? d  : bd[j];
                    bi[j] = sw ? id : bi[j];
                    d  = sw ? od : d;
                    id = sw ? oi : id;
                }
            }
        }
    } else {
        // Phase C: EXACT d2 recompute + EXACT batch check + lexicographic
        // (d, idx) insert (order-independent-exact).
        for (int s = 0; s < cnt; ++s) {
            const int i = (int)seg[s*32];
            const float4 a = pos4[i];
            const float dot = fmaf(pz, a.z, fmaf(py, a.y, __fmul_rn(px, a.x)));
            const float d2 = __fsub_rn(__fadd_rn(pn2, a.w), 2.0f * dot);
            if (abatch[i] == pb && d2 <= bd[KNN-1]) {
                float d = d2; int id = i;
                #pragma unroll
                for (int j = 0; j < KNN; ++j) {
                    const bool sw = (d < bd[j]) || (d == bd[j] && id < bi[j]);
                    const float od = bd[j]; const int oi = bi[j];
                    bd[j] = sw ? d  : bd[j];
                    bi[j] = sw ? id : bi[j];
                    d  = sw ? od : d;
                    id = sw ? oi : id;
                }
            }
        }
    }

    // final merge: 16x pop-min over 32 lanes, lexicographic (d, idx)
    #pragma unroll
    for (int k = 0; k < KNN; ++k) {
        float d = bd[0]; int i = bi[0];
        #pragma unroll
        for (int m = 1; m <= 16; m <<= 1) {
            const float pd = __shfl_xor(d, m);
            const int   pi = __shfl_xor(i, m);
            const bool take = (pd < d) || (pd == d && pi < i);
            d = take ? pd : d;
            i = take ? pi : i;
        }
        idxk[k] = i;
        const bool win = (bd[0] == d) && (bi[0] == i);
        if (win) {
            #pragma unroll
            for (int j = 0; j < KNN-1; ++j) { bd[j] = bd[j+1]; bi[j] = bi[j+1]; }
            bd[KNN-1] = FLT_MAX; bi[KNN-1] = 0x7fffffff;
        }
    }
}

// ---------------------------------------------------------------------------
// Kernel B: 32-lane groups, 2 POINTS per group (1024 blocks, ~36 KB LDS
//   -> 4 blocks/CU). r14-validated schedule + pre-scaled staging:
//   staged atoms stored as (-2x,-2y,-2z,a2) so the screen value is a pure
//   3-FMA chain: lhs' = fma(pz,bz, fma(py,by, fma(px,bx, a2))).
//   tau and the filter share lhs'-space (validity argument space-agnostic);
//   slack 1e-2 >> 2*|d2-(pn2+lhs')| ~ 2e-4; phase C recomputes EXACT d2.
// ---------------------------------------------------------------------------
__global__ void __launch_bounds__(256) atom_main_kernel(
    const float* __restrict__ xyz,
    const int*   __restrict__ batch,
    const float4* __restrict__ pos4,
    const float* __restrict__ tbuf,
    const int*   __restrict__ abatch,
    const float* __restrict__ Watt,
    const float* __restrict__ We1, const float* __restrict__ be1,
    const float* __restrict__ We2, const float* __restrict__ be2,
    const float* __restrict__ We3, const float* __restrict__ be3,
    float* __restrict__ out)
{
    __shared__ float lw1t[CH*CH], lw2t[CH*CH], lw3t[CH*CH];
    __shared__ float lb1[CH], lb2[CH], lb3[CH], lwatt[KNN];
    __shared__ unsigned short lbuf[GROUPS_PER_BLOCK * PTSPG * SLOTS * 32];
    __shared__ float4 lpos[2][CHUNK];
    const int tid = threadIdx.x;
    lw1t[tid] = We1[(tid & 15)*CH + (tid >> 4)];
    lw2t[tid] = We2[(tid & 15)*CH + (tid >> 4)];
    lw3t[tid] = We3[(tid & 15)*CH + (tid >> 4)];
    if (tid < CH) { lb1[tid] = be1[tid]; lb2[tid] = be2[tid]; lb3[tid] = be3[tid]; lwatt[tid] = Watt[tid]; }

    const int c32 = tid & 31;
    const int grp = tid >> 5;
    const int n0  = (blockIdx.x * GROUPS_PER_BLOCK + grp) * PTSPG;
    const int n1  = n0 + 1;

    const float px0 = xyz[n0*3+0], py0 = xyz[n0*3+1], pz0 = xyz[n0*3+2];
    const float px1 = xyz[n1*3+0], py1 = xyz[n1*3+1], pz1 = xyz[n1*3+2];
    // np: sum(x*x, -1) sequential, no FMA
    const float pn20 = __fadd_rn(__fadd_rn(__fmul_rn(px0,px0), __fmul_rn(py0,py0)), __fmul_rn(pz0,pz0));
    const float pn21 = __fadd_rn(__fadd_rn(__fmul_rn(px1,px1), __fmul_rn(py1,py1)), __fmul_rn(pz1,pz1));
    const int pb0 = batch[n0];
    const int pb1 = batch[n1];

    // prologue: stage chunk 0 into buffer 0 (pre-scaled; -2*x is exact)
    {
        const float4 q0 = pos4[tid];
        const float4 q1 = pos4[tid+256];
        lpos[0][tid]     = make_float4(-2.0f*q0.x, -2.0f*q0.y, -2.0f*q0.z, q0.w);
        lpos[0][tid+256] = make_float4(-2.0f*q1.x, -2.0f*q1.y, -2.0f*q1.z, q1.w);
    }

    float vmin0 = FLT_MAX, vmin1 = FLT_MAX;
    float tauf0 = 0.0f, tauf1 = 0.0f;
    int   skip0 = 0, skip1 = 0;
    int   cnt0 = 0, cnt1 = 0;
    unsigned short* seg0 = &lbuf[(grp*PTSPG + 0) * (SLOTS*32) + c32];
    unsigned short* seg1 = &lbuf[(grp*PTSPG + 1) * (SLOTS*32) + c32];

    for (int g = 0; g < NPASS; ++g) {
        const int cur = g & 1;
        __syncthreads();                     // buf[cur] ready; buf[cur^1] free
        // issue next-chunk loads AFTER the barrier (not drained by it)
        float4 q0, q1;
        const bool pf = (g+1 < NPASS);
        if (pf) {
            const int nc = (g+1 < VMINC) ? (g+1) : (g+1-VMINC);
            const int base = nc*CHUNK;
            q0 = pos4[base+tid]; q1 = pos4[base+tid+256];
        }
        if (g == VMINC) {
            // per-point tau: 16 d-only pop-mins over 32 lane minima (lhs'-
            // space). Validity: each pop removes >=1 lane = >=1 distinct
            // in-batch atom with lhs' <= tau.
            float tau0 = FLT_MAX, tau1 = FLT_MAX;
            {
                float v = vmin0;
                #pragma unroll
                for (int k = 0; k < KNN; ++k) {
                    float d = v;
                    d = fminf(d, __shfl_xor(d, 1));
                    d = fminf(d, __shfl_xor(d, 2));
                    d = fminf(d, __shfl_xor(d, 4));
                    d = fminf(d, __shfl_xor(d, 8));
                    d = fminf(d, __shfl_xor(d, 16));
                    tau0 = d;
                    if (v == d) v = FLT_MAX; // remove popped (ties safe)
                }
            }
            {
                float v = vmin1;
                #pragma unroll
                for (int k = 0; k < KNN; ++k) {
                    float d = v;
                    d = fminf(d, __shfl_xor(d, 1));
                    d = fminf(d, __shfl_xor(d, 2));
                    d = fminf(d, __shfl_xor(d, 4));
                    d = fminf(d, __shfl_xor(d, 8));
                    d = fminf(d, __shfl_xor(d, 16));
                    tau1 = d;
                    if (v == d) v = FLT_MAX;
                }
            }
            skip0 = !(tau0 < BIGF);          // group-uniform
            skip1 = !(tau1 < BIGF);
            tauf0 = skip0 ? -FLT_MAX : tau0 + (1e-5f*(fabsf(pn20) + fabsf(tau0)) + 1e-2f);
            tauf1 = skip1 ? -FLT_MAX : tau1 + (1e-5f*(fabsf(pn21) + fabsf(tau1)) + 1e-2f);
        }
        if (g < VMINC) {
            // dual vmin scan (subset chunks 0..3); lazy global batch check
            #pragma unroll 4
            for (int t = 0; t < CHUNK/32; ++t) {
                const int il = t*32 + c32;
                const float4 a = lpos[cur][il];
                const float lhs0 = fmaf(pz0, a.z, fmaf(py0, a.y, fmaf(px0, a.x, a.w)));
                const float lhs1 = fmaf(pz1, a.z, fmaf(py1, a.y, fmaf(px1, a.x, a.w)));
                if (lhs0 < vmin0) { if (abatch[g*CHUNK + il] == pb0) vmin0 = lhs0; }
                if (lhs1 < vmin1) { if (abatch[g*CHUNK + il] == pb1) vmin1 = lhs1; }
            }
        } else {
            // dual lean distance-only filter scan (3 FMA + cmp per point)
            const int cb = g - VMINC;
            #pragma unroll 4
            for (int t = 0; t < CHUNK/32; ++t) {
                const int il = t*32 + c32;
                const float4 a = lpos[cur][il];
                const float lhs0 = fmaf(pz0, a.z, fmaf(py0, a.y, fmaf(px0, a.x, a.w)));
                const float lhs1 = fmaf(pz1, a.z, fmaf(py1, a.y, fmaf(px1, a.x, a.w)));
                const int gi = cb*CHUNK + il;
                if (lhs0 <= tauf0) {
                    if (cnt0 < SLOTS) seg0[cnt0*32] = (unsigned short)gi;
                    ++cnt0;
                }
                if (lhs1 <= tauf1) {
                    if (cnt1 < SLOTS) seg1[cnt1*32] = (unsigned short)gi;
                    ++cnt1;
                }
            }
        }
        if (pf) {                            // write-late: loads landed by now
            lpos[cur^1][tid]     = make_float4(-2.0f*q0.x, -2.0f*q0.y, -2.0f*q0.z, q0.w);
            lpos[cur^1][tid+256] = make_float4(-2.0f*q1.x, -2.0f*q1.y, -2.0f*q1.z, q1.w);
        }
    }

    // ---- tails (validated): exact selection per point
    int idxk0[KNN], idxk1[KNN];
    knn_tail(c32, px0, py0, pz0, pn20, pb0, skip0, cnt0, seg0, pos4, abatch, idxk0);
    knn_tail(c32, px1, py1, pz1, pn21, pb1, skip1, cnt1, seg1, pos4, abatch, idxk1);

    // ---- packed epilogue: lanes 0-15 -> point0, lanes 16-31 -> point1.
    {
        const int half = (tid >> 4) & 1;
        const int c = tid & 15;
        const int myn = half ? n1 : n0;
        const float px = half ? px1 : px0;
        const float py = half ? py1 : py0;
        const float pz = half ? pz1 : pz0;
        int myidx[KNN];
        #pragma unroll
        for (int k = 0; k < KNN; ++k) myidx[k] = half ? idxk1[k] : idxk0[k];

        float ac0 = 0.0f, ac1 = 0.0f, ac2 = 0.0f;
        #pragma unroll
        for (int k = 0; k < KNN; ++k) {
            const int j = myidx[k];
            const float4 a = pos4[j];
            const float v0 = __fsub_rn(px, a.x);
            const float v1 = __fsub_rn(py, a.y);
            const float v2 = __fsub_rn(pz, a.z);
            // np: dists = sum(vecs*vecs, -1), sequential, no FMA (recomputed)
            const float dist = __fadd_rn(__fadd_rn(__fmul_rn(v0,v0), __fmul_rn(v1,v1)), __fmul_rn(v2,v2));
            const float w = 1.0f / __fadd_rn(dist, 1e-8f);   // power(x, -1.0)
            const float nv0 = __fmul_rn(v0, w);
            const float nv1 = __fmul_rn(v1, w);
            const float nv2 = __fmul_rn(v2, w);
            const float fc = tbuf[(size_t)j * CH + c];
            const float fw = __fmul_rn(fc, lwatt[k]);
            ac0 = fmaf(nv0, fw, ac0);
            ac1 = fmaf(nv1, fw, ac1);
            ac2 = fmaf(nv2, fw, ac2);
        }
        const float s = __fadd_rn(__fadd_rn(__fmul_rn(ac0,ac0), __fmul_rn(ac1,ac1)),
                                  __fmul_rn(ac2,ac2));
        const float fx = sqrtf(s);

        float a1 = 0.0f;
        #pragma unroll
        for (int j = 0; j < CH; ++j) {
            const float fj = __shfl(fx, j, 16);
            a1 = fmaf(lw1t[j*CH + c], fj, a1);
        }
        const float g1 = leakyf(a1 + lb1[c]);

        float a2 = 0.0f;
        #pragma unroll
        for (int j = 0; j < CH; ++j) {
            const float gj = __shfl(g1, j, 16);
            a2 = fmaf(lw2t[j*CH + c], gj, a2);
        }
        const float g2 = leakyf(a2 + lb2[c]);

        float a3 = 0.0f;
        #pragma unroll
        for (int j = 0; j < CH; ++j) {
            const float gj = __shfl(g2, j, 16);
            a3 = fmaf(lw3t[j*CH + c], gj, a3);
        }
        out[(size_t)myn*CH + c] = a3 + lb3[c];
    }
}

// ---------------------------------------------------------------------------
extern "C" void kernel_launch(void* const* d_in, const int* in_sizes, int n_in,
                              void* d_out, int out_size, void* d_ws, size_t ws_size,
                              hipStream_t stream)
{
    (void)in_sizes; (void)n_in; (void)out_size; (void)ws_size;
    const float* xyz        = (const float*)d_in[0];
    const float* atom_xyz   = (const float*)d_in[1];
    const float* atomtypes  = (const float*)d_in[2];
    const int*   batch      = (const int*)d_in[3];
    const int*   atom_batch = (const int*)d_in[4];
    const float* Wt1 = (const float*)d_in[5];
    const float* bt1 = (const float*)d_in[6];
    const float* Wt2 = (const float*)d_in[7];
    const float* bt2 = (const float*)d_in[8];
    const float* Wt3 = (const float*)d_in[9];
    const float* bt3 = (const float*)d_in[10];
    const float* Watt = (const float*)d_in[11];
    const float* We1 = (const float*)d_in[12];
    const float* be1 = (const float*)d_in[13];
    const float* We2 = (const float*)d_in[14];
    const float* be2 = (const float*)d_in[15];
    const float* We3 = (const float*)d_in[16];
    const float* be3 = (const float*)d_in[17];

    char* ws = (char*)d_ws;
    float4* pos4  = (float4*)ws;                          // 8192*16  = 131072 B
    float*  tbuf  = (float*)(ws + 131072);                // 8192*64  = 524288 B
    int*    abat  = (int*)(ws + 131072 + 524288);         // 8192*4   =  32768 B
    float*  out   = (float*)d_out;

    hipLaunchKernelGGL(prep_kernel, dim3(MATOMS/256), dim3(256), 0, stream,
                       atom_xyz, atomtypes, atom_batch,
                       Wt1, bt1, Wt2, bt2, Wt3, bt3,
                       pos4, tbuf, abat);
    hipLaunchKernelGGL(atom_main_kernel, dim3(NPTS/(GROUPS_PER_BLOCK*PTSPG)), dim3(256), 0, stream,
                       xyz, batch, pos4, tbuf, abat,
                       Watt, We1, be1, We2, be2, We3, be3,
                       out);
}